// Round 6
// baseline (315.655 us; speedup 1.0000x reference)
//
#include <hip/hip_runtime.h>
#include <hip/hip_cooperative_groups.h>

namespace cg = cooperative_groups;

#define NPTS   65536
#define TOTAL  (2 * NPTS)
#define NUNITS 1024            // units of 128 points
#define CGRID  512

typedef __attribute__((ext_vector_type(8)))  short short8;
typedef __attribute__((ext_vector_type(16))) float float16;
union F8 { uint4 u; short8 s; };

// ws byte offsets
#define WS_STRIPE 0                               // fp32[16][128], memset 0
#define WS_T1A    8192                            // bf16[TOTAL][32] f_nei, 64B rows
#define WS_T1B    (8192 + TOTAL * 64)             // bf16[TOTAL][4]  f_xyz, 8B rows
#define WS_T2     (8192 + TOTAL * 64 + TOTAL * 8) // bf16[TOTAL][32] feat, 64B rows

__device__ __forceinline__ unsigned short f2bf(float x) {
    unsigned u = __float_as_uint(x);
    return (unsigned short)((u + 0x7FFFu + ((u >> 16) & 1u)) >> 16);
}
__device__ __forceinline__ unsigned pk2(float a, float b) {
    return (unsigned)f2bf(a) | ((unsigned)f2bf(b) << 16);
}
__device__ __forceinline__ float relu(float x) { return x > 0.f ? x : 0.f; }
__device__ __forceinline__ uint4 pk8(const float* e) {
    uint4 u;
    u.x = pk2(e[0], e[1]); u.y = pk2(e[2], e[3]);
    u.z = pk2(e[4], e[5]); u.w = pk2(e[6], e[7]);
    return u;
}
__device__ __forceinline__ float16 zero16() {
    float16 z;
#pragma unroll
    for (int i = 0; i < 16; i++) z[i] = 0.f;
    return z;
}

// ===== P0: tnet trunk + block max + striped atomics; f_nei GEMM + feat copy =====
__device__ __forceinline__ void phase0(int blk, int nblk,
    const float* __restrict__ feature, const float* __restrict__ xyz,
    const float* __restrict__ tW1, const float* __restrict__ ts1, const float* __restrict__ tb1,
    const float* __restrict__ tW2, const float* __restrict__ ts2, const float* __restrict__ tb2,
    const float* __restrict__ W2,  const float* __restrict__ s2,  const float* __restrict__ b2,
    float* __restrict__ stripe, unsigned short* __restrict__ t1a, unsigned short* __restrict__ t2,
    float (*red)[64])
{
    const int lane = threadIdx.x & 63, wv = threadIdx.x >> 6;
    const int col = lane & 31, h = lane >> 5;
    const float16 z = zero16();
    float e[8];
    // trunk weights: tW1*ts1 (VALU side), tW2^T*ts2 (B-frags)
    float aw0[8], aw1[8], aw2[8], bb[8];
#pragma unroll
    for (int j = 0; j < 8; j++) {
        int k = 8 * h + j; float s = ts1[k];
        aw0[j] = tW1[k] * s; aw1[j] = tW1[16 + k] * s; aw2[j] = tW1[32 + k] * s;
        bb[j] = tb1[k];
    }
    F8 bf0, bf1;
#pragma unroll
    for (int j = 0; j < 8; j++) e[j] = tW2[(8 * h + j) * 64 + col] * ts2[col];
    bf0.u = pk8(e);
#pragma unroll
    for (int j = 0; j < 8; j++) e[j] = tW2[(8 * h + j) * 64 + 32 + col] * ts2[32 + col];
    bf1.u = pk8(e);
    // f_nei weights: W2^T folded as A-frags
    F8 a0, a1;
    float sc2 = s2[col];
#pragma unroll
    for (int j = 0; j < 8; j++) e[j] = W2[(8 * h + j) * 32 + col] * sc2;
    a0.u = pk8(e);
#pragma unroll
    for (int j = 0; j < 8; j++) e[j] = W2[(16 + 8 * h + j) * 32 + col] * sc2;
    a1.u = pk8(e);
    float b2v[16];
#pragma unroll
    for (int r = 0; r < 16; r++) b2v[r] = b2[(r & 3) + 8 * (r >> 2) + 4 * h];

    for (int u = blk; u < NUNITS; u += nblk) {
        int base = u * 128 + wv * 32;
        int b = u >> 9;
        // trunk + max
        const float* xp = xyz + (size_t)(base + col) * 3;
        float x0 = xp[0], x1 = xp[1], x2 = xp[2];
        float hv[8];
#pragma unroll
        for (int j = 0; j < 8; j++)
            hv[j] = relu(x0 * aw0[j] + x1 * aw1[j] + x2 * aw2[j] + bb[j]);
        F8 af; af.u = pk8(hv);
        float16 c0 = __builtin_amdgcn_mfma_f32_32x32x16_bf16(af.s, bf0.s, z, 0, 0, 0);
        float16 c1 = __builtin_amdgcn_mfma_f32_32x32x16_bf16(af.s, bf1.s, z, 0, 0, 0);
        float v0 = c0[0], v1 = c1[0];
#pragma unroll
        for (int i = 1; i < 16; i++) { v0 = fmaxf(v0, c0[i]); v1 = fmaxf(v1, c1[i]); }
        v0 = fmaxf(v0, __shfl_xor(v0, 32));
        v1 = fmaxf(v1, __shfl_xor(v1, 32));
        if (h == 0) { red[wv][col] = v0; red[wv][32 + col] = v1; }
        __syncthreads();
        if (threadIdx.x < 64) {
            int c = threadIdx.x;
            float m = fmaxf(fmaxf(red[0][c], red[1][c]), fmaxf(red[2][c], red[3][c]));
            float val = relu(m + tb2[c]);      // bias/relu after max: monotone, valid
            atomicMax((unsigned*)(stripe + (blk & 15) * 128 + b * 64 + c),
                      __float_as_uint(val));
        }
        // f_nei GEMM + raw feat copy
        int pt = base + col;
        const float* fb = feature + (size_t)b * 32 * NPTS + (pt & (NPTS - 1));
        float v[8];
        F8 f0, f1;
#pragma unroll
        for (int j = 0; j < 8; j++) v[j] = fb[(size_t)(8 * h + j) * NPTS];
        f0.u = pk8(v);
#pragma unroll
        for (int j = 0; j < 8; j++) v[j] = fb[(size_t)(16 + 8 * h + j) * NPTS];
        f1.u = pk8(v);
        *(uint4*)(t2 + (size_t)pt * 32 + 8 * h) = f0.u;
        *(uint4*)(t2 + (size_t)pt * 32 + 16 + 8 * h) = f1.u;
        float16 acc = z;
        acc = __builtin_amdgcn_mfma_f32_32x32x16_bf16(a0.s, f0.s, acc, 0, 0, 0);
        acc = __builtin_amdgcn_mfma_f32_32x32x16_bf16(a1.s, f1.s, acc, 0, 0, 0);
#pragma unroll
        for (int q = 0; q < 4; q++) {
            int r = 4 * q;
            uint2 uu;
            uu.x = pk2(relu(acc[r] + b2v[r]), relu(acc[r + 1] + b2v[r + 1]));
            uu.y = pk2(relu(acc[r + 2] + b2v[r + 2]), relu(acc[r + 3] + b2v[r + 3]));
            *(uint2*)(t1a + (size_t)pt * 32 + 8 * q + 4 * h) = uu;
        }
        __syncthreads();                        // protect red[] reuse next unit
    }
}

// ===== P1: tnet head (butterfly matvec) + f_xyz =====
__device__ __forceinline__ void phase1(int blk, int nblk,
    const float* __restrict__ xyz,
    const float* __restrict__ tW3, const float* __restrict__ ts3, const float* __restrict__ tb3,
    const float* __restrict__ tW4, const float* __restrict__ tb4,
    const float* __restrict__ W1,  const float* __restrict__ s1, const float* __restrict__ b1,
    const float* __restrict__ stripe, unsigned short* __restrict__ t1b)
{
    const int lane = threadIdx.x & 63, wv = threadIdx.x >> 6;
    const int col = lane & 31, h = lane >> 5;
    for (int u = blk; u < NUNITS; u += nblk) {
        int b = u >> 9;
        float hm = 0.f;                         // stripes >= 0; 0-init safe under max
#pragma unroll
        for (int s = 0; s < 16; s++)
            hm = fmaxf(hm, stripe[s * 128 + b * 64 + lane]);
        float v[16];                            // lane i contributes hm_i * tW3[i][:]
        const float4* trow = (const float4*)(tW3 + lane * 16);
#pragma unroll
        for (int q = 0; q < 4; q++) {
            float4 t4 = trow[q];
            v[4 * q + 0] = hm * t4.x; v[4 * q + 1] = hm * t4.y;
            v[4 * q + 2] = hm * t4.z; v[4 * q + 3] = hm * t4.w;
        }
#pragma unroll
        for (int off = 1; off < 64; off <<= 1) {
#pragma unroll
            for (int c = 0; c < 16; c++) v[c] += __shfl_xor(v[c], off);
        }
        float T[9];
#pragma unroll
        for (int j = 0; j < 9; j++) T[j] = tb4[j];
#pragma unroll
        for (int c = 0; c < 16; c++) {
            float h3 = relu(v[c] * ts3[c] + tb3[c]);
#pragma unroll
            for (int j = 0; j < 9; j++) T[j] += h3 * tW4[c * 9 + j];
        }
        T[0] += 1.f; T[4] += 1.f; T[8] += 1.f;

        int pt = u * 128 + wv * 32 + col;
        const float* xp = xyz + (size_t)pt * 3;
        float x0 = xp[0], x1 = xp[1], x2 = xp[2];
        float q0 = x0 * T[0] + x1 * T[3] + x2 * T[6];
        float q1 = x0 * T[1] + x1 * T[4] + x2 * T[7];
        float q2 = x0 * T[2] + x1 * T[5] + x2 * T[8];
        float r0 = relu((q0 * W1[0] + q1 * W1[3] + q2 * W1[6]) * s1[0] + b1[0]);
        float r1 = relu((q0 * W1[1] + q1 * W1[4] + q2 * W1[7]) * s1[1] + b1[1]);
        float r2 = relu((q0 * W1[2] + q1 * W1[5] + q2 * W1[8]) * s1[2] + b1[2]);
        if (h == 0) {
            uint2 uu; uu.x = pk2(r0, r1); uu.y = pk2(r2, 0.f);
            *(uint2*)(t1b + (size_t)pt * 4) = uu;
        }
    }
}

// ===== P2+P3 fused: gather GEMM + max-over-K (m in LDS) + output GEMM =====
__device__ __forceinline__ void phase23(int blk, int nblk,
    const int* __restrict__ nidx,
    const float* __restrict__ W3, const float* __restrict__ s3, const float* __restrict__ b3,
    const float* __restrict__ W4, const float* __restrict__ s4, const float* __restrict__ b4,
    const unsigned short* __restrict__ t1a, const unsigned short* __restrict__ t1b,
    const unsigned short* __restrict__ t2, float* __restrict__ out,
    unsigned short* __restrict__ mld /* [128][36] */)
{
    const int lane = threadIdx.x & 63, wv = threadIdx.x >> 6;
    const int col = lane & 31, h = lane >> 5;
    const float16 z = zero16();
    float e[8];
    // W3^T folded B-frags (k>=35 zero)
    F8 w0, w1, w2, zf;
    zf.u.x = zf.u.y = zf.u.z = zf.u.w = 0u;
    float sc3 = s3[col];
#pragma unroll
    for (int j = 0; j < 8; j++) e[j] = W3[(8 * h + j) * 32 + col] * sc3;
    w0.u = pk8(e);
#pragma unroll
    for (int j = 0; j < 8; j++) e[j] = W3[(16 + 8 * h + j) * 32 + col] * sc3;
    w1.u = pk8(e);
    w2 = zf;
    if (h == 0) {
        float e2[8] = {0.f, 0.f, 0.f, 0.f, 0.f, 0.f, 0.f, 0.f};
#pragma unroll
        for (int j = 0; j < 3; j++) e2[j] = W3[(32 + j) * 32 + col] * sc3;
        w2.u = pk8(e2);
    }
    float b3v = b3[col];
    // W4^T folded A-frags
    F8 aw[4];
    float sc4 = s4[col];
#pragma unroll
    for (int t = 0; t < 4; t++) {
#pragma unroll
        for (int j = 0; j < 8; j++) e[j] = W4[(16 * t + 8 * h + j) * 32 + col] * sc4;
        aw[t].u = pk8(e);
    }
    float b4v[16];
#pragma unroll
    for (int r = 0; r < 16; r++) b4v[r] = b4[(r & 3) + 8 * (r >> 2) + 4 * h];

    // XCD-batch affinity: blk&7 is the XCD slot; slot>=4 -> batch 1
    int per = NUNITS / nblk;
    int slot = blk & 7, batch = slot >> 2;
    int grp = (blk >> 3) * 4 + (slot & 3);      // within-batch block id in [0, nblk/2)
    for (int i = 0; i < per; i++) {
        int u = batch * 512 + i * (nblk >> 1) + grp;
        int base = u * 128;
        // P2: 16 pairs (32 pts) per wave, m -> LDS
        int idx_n = nidx[(base + 2 * (wv * 16)) * 16 + col];
        for (int it = 0; it < 16; it++) {
            int pi = wv * 16 + it;
            int base_pt = base + 2 * pi;
            int idx = idx_n;
            if (it < 15) idx_n = nidx[(base_pt + 2) * 16 + col];
            size_t row = ((size_t)batch << 16) + (unsigned)idx;
            const unsigned short* ap = t1a + row * 32;
            F8 ga0, ga1, ga2;
            ga0.u = *(const uint4*)(ap + 8 * h);
            ga1.u = *(const uint4*)(ap + 16 + 8 * h);
            ga2 = zf;
            if (h == 0) {
                uint2 q = *(const uint2*)(t1b + row * 4);
                ga2.u.x = q.x; ga2.u.y = q.y;
            }
            float16 acc = z;
            acc = __builtin_amdgcn_mfma_f32_32x32x16_bf16(ga0.s, w0.s, acc, 0, 0, 0);
            acc = __builtin_amdgcn_mfma_f32_32x32x16_bf16(ga1.s, w1.s, acc, 0, 0, 0);
            acc = __builtin_amdgcn_mfma_f32_32x32x16_bf16(ga2.s, w2.s, acc, 0, 0, 0);
            float vA = acc[0], vB = acc[8];
#pragma unroll
            for (int r = 1; r < 8; r++) { vA = fmaxf(vA, acc[r]); vB = fmaxf(vB, acc[8 + r]); }
            vA = fmaxf(vA, __shfl_xor(vA, 32));
            vB = fmaxf(vB, __shfl_xor(vB, 32));
            vA = relu(vA + b3v);
            vB = relu(vB + b3v);
            float val = h ? vB : vA;
            mld[(2 * pi + h) * 36 + col] = f2bf(val);   // same-wave produce/consume
        }
        // P3: 32 pts per wave; m read back from LDS (same wave -> no barrier)
        int p_loc = wv * 32 + col;
        int p = base + p_loc;
        const unsigned short* bp = t2 + (size_t)p * 32 + 8 * h;
        F8 x0, x1, x2, x3;
        x0.u = *(const uint4*)(bp);
        x1.u = *(const uint4*)(bp + 16);
        const unsigned short* mp = mld + p_loc * 36;
        uint2 q0 = *(const uint2*)(mp + 8 * h);
        uint2 q1 = *(const uint2*)(mp + 8 * h + 4);
        uint2 q2 = *(const uint2*)(mp + 16 + 8 * h);
        uint2 q3 = *(const uint2*)(mp + 16 + 8 * h + 4);
        x2.u.x = q0.x; x2.u.y = q0.y; x2.u.z = q1.x; x2.u.w = q1.y;
        x3.u.x = q2.x; x3.u.y = q2.y; x3.u.z = q3.x; x3.u.w = q3.y;
        float16 acc = z;
        acc = __builtin_amdgcn_mfma_f32_32x32x16_bf16(aw[0].s, x0.s, acc, 0, 0, 0);
        acc = __builtin_amdgcn_mfma_f32_32x32x16_bf16(aw[1].s, x1.s, acc, 0, 0, 0);
        acc = __builtin_amdgcn_mfma_f32_32x32x16_bf16(aw[2].s, x2.s, acc, 0, 0, 0);
        acc = __builtin_amdgcn_mfma_f32_32x32x16_bf16(aw[3].s, x3.s, acc, 0, 0, 0);
        float* ob = out + (size_t)(batch * 32) * NPTS + (p & (NPTS - 1));
#pragma unroll
        for (int r = 0; r < 16; r++) {
            int o = (r & 3) + 8 * (r >> 2) + 4 * h;
            ob[(size_t)o * NPTS] = relu(acc[r] + b4v[r]);
        }
    }
}

#define ALL_ARGS feature, xyz, nidx, tW1, ts1, tb1, tW2, ts2, tb2, \
                 tW3, ts3, tb3, tW4, tb4, W1, s1, b1, W2, s2, b2, \
                 W3, s3, b3, W4, s4, b4
#define ALL_PARAMS const float* __restrict__ feature, const float* __restrict__ xyz, \
    const int* __restrict__ nidx, \
    const float* __restrict__ tW1, const float* __restrict__ ts1, const float* __restrict__ tb1, \
    const float* __restrict__ tW2, const float* __restrict__ ts2, const float* __restrict__ tb2, \
    const float* __restrict__ tW3, const float* __restrict__ ts3, const float* __restrict__ tb3, \
    const float* __restrict__ tW4, const float* __restrict__ tb4, \
    const float* __restrict__ W1, const float* __restrict__ s1, const float* __restrict__ b1, \
    const float* __restrict__ W2, const float* __restrict__ s2, const float* __restrict__ b2, \
    const float* __restrict__ W3, const float* __restrict__ s3, const float* __restrict__ b3, \
    const float* __restrict__ W4, const float* __restrict__ s4, const float* __restrict__ b4

__global__ __launch_bounds__(256) void fused_coop(ALL_PARAMS, char* ws, float* out)
{
    __shared__ float red[4][64];
    __shared__ unsigned short mld[128 * 36];
    float* stripe = (float*)(ws + WS_STRIPE);
    unsigned short* t1a = (unsigned short*)(ws + WS_T1A);
    unsigned short* t1b = (unsigned short*)(ws + WS_T1B);
    unsigned short* t2  = (unsigned short*)(ws + WS_T2);
    cg::grid_group g = cg::this_grid();
    phase0(blockIdx.x, gridDim.x, feature, xyz, tW1, ts1, tb1, tW2, ts2, tb2,
           W2, s2, b2, stripe, t1a, t2, red);
    g.sync();
    phase1(blockIdx.x, gridDim.x, xyz, tW3, ts3, tb3, tW4, tb4, W1, s1, b1, stripe, t1b);
    g.sync();
    phase23(blockIdx.x, gridDim.x, nidx, W3, s3, b3, W4, s4, b4, t1a, t1b, t2, out, mld);
}

__global__ __launch_bounds__(256) void kP0(ALL_PARAMS, char* ws, float* out)
{
    __shared__ float red[4][64];
    (void)out;
    phase0(blockIdx.x, gridDim.x, feature, xyz, tW1, ts1, tb1, tW2, ts2, tb2,
           W2, s2, b2, (float*)(ws + WS_STRIPE),
           (unsigned short*)(ws + WS_T1A), (unsigned short*)(ws + WS_T2), red);
}
__global__ __launch_bounds__(256) void kP1(ALL_PARAMS, char* ws, float* out)
{
    (void)out;
    phase1(blockIdx.x, gridDim.x, xyz, tW3, ts3, tb3, tW4, tb4, W1, s1, b1,
           (const float*)(ws + WS_STRIPE), (unsigned short*)(ws + WS_T1B));
}
__global__ __launch_bounds__(256) void kP23(ALL_PARAMS, char* ws, float* out)
{
    __shared__ unsigned short mld[128 * 36];
    phase23(blockIdx.x, gridDim.x, nidx, W3, s3, b3, W4, s4, b4,
            (const unsigned short*)(ws + WS_T1A), (const unsigned short*)(ws + WS_T1B),
            (const unsigned short*)(ws + WS_T2), out, mld);
}

extern "C" void kernel_launch(void* const* d_in, const int* in_sizes, int n_in,
                              void* d_out, int out_size, void* d_ws, size_t ws_size,
                              hipStream_t stream)
{
    const float* feature = (const float*)d_in[0];
    const float* xyz     = (const float*)d_in[1];
    const int*   nidx    = (const int*)d_in[2];
    const float* tW1 = (const float*)d_in[3];
    const float* ts1 = (const float*)d_in[4];
    const float* tb1 = (const float*)d_in[5];
    const float* tW2 = (const float*)d_in[6];
    const float* ts2 = (const float*)d_in[7];
    const float* tb2 = (const float*)d_in[8];
    const float* tW3 = (const float*)d_in[9];
    const float* ts3 = (const float*)d_in[10];
    const float* tb3 = (const float*)d_in[11];
    const float* tW4 = (const float*)d_in[12];
    const float* tb4 = (const float*)d_in[13];
    const float* W1  = (const float*)d_in[14];
    const float* s1  = (const float*)d_in[15];
    const float* b1  = (const float*)d_in[16];
    const float* W2  = (const float*)d_in[17];
    const float* s2  = (const float*)d_in[18];
    const float* b2  = (const float*)d_in[19];
    const float* W3  = (const float*)d_in[20];
    const float* s3  = (const float*)d_in[21];
    const float* b3  = (const float*)d_in[22];
    const float* W4  = (const float*)d_in[23];
    const float* s4  = (const float*)d_in[24];
    const float* b4  = (const float*)d_in[25];
    (void)in_sizes; (void)n_in; (void)out_size; (void)ws_size;

    char* wsp = (char*)d_ws;
    float* outp = (float*)d_out;

    hipMemsetAsync(wsp + WS_STRIPE, 0, 16 * 128 * sizeof(float), stream);

    void* args[] = {
        (void*)&feature, (void*)&xyz, (void*)&nidx,
        (void*)&tW1, (void*)&ts1, (void*)&tb1,
        (void*)&tW2, (void*)&ts2, (void*)&tb2,
        (void*)&tW3, (void*)&ts3, (void*)&tb3,
        (void*)&tW4, (void*)&tb4,
        (void*)&W1, (void*)&s1, (void*)&b1,
        (void*)&W2, (void*)&s2, (void*)&b2,
        (void*)&W3, (void*)&s3, (void*)&b3,
        (void*)&W4, (void*)&s4, (void*)&b4,
        (void*)&wsp, (void*)&outp};
    hipError_t err = hipLaunchCooperativeKernel((void*)fused_coop, dim3(CGRID), dim3(256),
                                                args, 0, stream);
    if (err != hipSuccess) {
        (void)hipGetLastError();   // clear sticky error, use plain-launch fallback
        kP0<<<NUNITS, 256, 0, stream>>>(ALL_ARGS, wsp, outp);
        kP1<<<NUNITS, 256, 0, stream>>>(ALL_ARGS, wsp, outp);
        kP23<<<NUNITS, 256, 0, stream>>>(ALL_ARGS, wsp, outp);
    }
}

// Round 7
// 160.734 us; speedup vs baseline: 1.9638x; 1.9638x over previous
//
#include <hip/hip_runtime.h>

#define NPTS   65536
#define TOTAL  (2 * NPTS)
#define NUNITS 1024            // units of 128 points

typedef __attribute__((ext_vector_type(8)))  short short8;
typedef __attribute__((ext_vector_type(16))) float float16;
union F8 { uint4 u; short8 s; };

// ws byte offsets
#define WS_STRIPE 0                               // fp32[16][128], memset 0
#define WS_T1A    8192                            // bf16[TOTAL][32] f_nei, 64B rows
#define WS_T1B    (8192 + TOTAL * 64)             // bf16[TOTAL][4]  f_xyz, 8B rows
#define WS_T2     (8192 + TOTAL * 64 + TOTAL * 8) // bf16[TOTAL][32] feat, 64B rows

__device__ __forceinline__ unsigned short f2bf(float x) {
    unsigned u = __float_as_uint(x);
    return (unsigned short)((u + 0x7FFFu + ((u >> 16) & 1u)) >> 16);
}
__device__ __forceinline__ unsigned pk2(float a, float b) {
    return (unsigned)f2bf(a) | ((unsigned)f2bf(b) << 16);
}
__device__ __forceinline__ float relu(float x) { return x > 0.f ? x : 0.f; }
__device__ __forceinline__ uint4 pk8(const float* e) {
    uint4 u;
    u.x = pk2(e[0], e[1]); u.y = pk2(e[2], e[3]);
    u.z = pk2(e[4], e[5]); u.w = pk2(e[6], e[7]);
    return u;
}
__device__ __forceinline__ float16 zero16() {
    float16 z;
#pragma unroll
    for (int i = 0; i < 16; i++) z[i] = 0.f;
    return z;
}

// ===== K0: tnet trunk + block max + striped atomics; f_nei GEMM + feat copy =====
__global__ __launch_bounds__(256) void kP0(
    const float* __restrict__ feature, const float* __restrict__ xyz,
    const float* __restrict__ tW1, const float* __restrict__ ts1, const float* __restrict__ tb1,
    const float* __restrict__ tW2, const float* __restrict__ ts2, const float* __restrict__ tb2,
    const float* __restrict__ W2,  const float* __restrict__ s2,  const float* __restrict__ b2,
    char* ws)
{
    __shared__ float red[4][64];
    float* stripe       = (float*)(ws + WS_STRIPE);
    unsigned short* t1a = (unsigned short*)(ws + WS_T1A);
    unsigned short* t2  = (unsigned short*)(ws + WS_T2);
    const int lane = threadIdx.x & 63, wv = threadIdx.x >> 6;
    const int col = lane & 31, h = lane >> 5;
    const float16 z = zero16();
    const int u = blockIdx.x;                   // 1024 blocks, 128 pts each
    const int b = u >> 9;
    float e[8];
    // trunk weights: tW1*ts1 (VALU side), tW2^T*ts2 (B-frags)
    float aw0[8], aw1[8], aw2[8], bb[8];
#pragma unroll
    for (int j = 0; j < 8; j++) {
        int k = 8 * h + j; float s = ts1[k];
        aw0[j] = tW1[k] * s; aw1[j] = tW1[16 + k] * s; aw2[j] = tW1[32 + k] * s;
        bb[j] = tb1[k];
    }
    F8 bf0, bf1;
#pragma unroll
    for (int j = 0; j < 8; j++) e[j] = tW2[(8 * h + j) * 64 + col] * ts2[col];
    bf0.u = pk8(e);
#pragma unroll
    for (int j = 0; j < 8; j++) e[j] = tW2[(8 * h + j) * 64 + 32 + col] * ts2[32 + col];
    bf1.u = pk8(e);
    // f_nei weights: W2^T folded as A-frags
    F8 a0, a1;
    float sc2 = s2[col];
#pragma unroll
    for (int j = 0; j < 8; j++) e[j] = W2[(8 * h + j) * 32 + col] * sc2;
    a0.u = pk8(e);
#pragma unroll
    for (int j = 0; j < 8; j++) e[j] = W2[(16 + 8 * h + j) * 32 + col] * sc2;
    a1.u = pk8(e);
    float b2v[16];
#pragma unroll
    for (int r = 0; r < 16; r++) b2v[r] = b2[(r & 3) + 8 * (r >> 2) + 4 * h];

    int base = u * 128 + wv * 32;
    // trunk + max
    const float* xp = xyz + (size_t)(base + col) * 3;
    float x0 = xp[0], x1 = xp[1], x2 = xp[2];
    float hv[8];
#pragma unroll
    for (int j = 0; j < 8; j++)
        hv[j] = relu(x0 * aw0[j] + x1 * aw1[j] + x2 * aw2[j] + bb[j]);
    F8 af; af.u = pk8(hv);
    float16 c0 = __builtin_amdgcn_mfma_f32_32x32x16_bf16(af.s, bf0.s, z, 0, 0, 0);
    float16 c1 = __builtin_amdgcn_mfma_f32_32x32x16_bf16(af.s, bf1.s, z, 0, 0, 0);
    float v0 = c0[0], v1 = c1[0];
#pragma unroll
    for (int i = 1; i < 16; i++) { v0 = fmaxf(v0, c0[i]); v1 = fmaxf(v1, c1[i]); }
    v0 = fmaxf(v0, __shfl_xor(v0, 32));
    v1 = fmaxf(v1, __shfl_xor(v1, 32));
    if (h == 0) { red[wv][col] = v0; red[wv][32 + col] = v1; }
    __syncthreads();
    if (threadIdx.x < 64) {
        int c = threadIdx.x;
        float m = fmaxf(fmaxf(red[0][c], red[1][c]), fmaxf(red[2][c], red[3][c]));
        float val = relu(m + tb2[c]);           // bias/relu after max: monotone, valid
        atomicMax((unsigned*)(stripe + (u & 15) * 128 + b * 64 + c), __float_as_uint(val));
    }
    // f_nei GEMM + raw feat copy
    int pt = base + col;
    const float* fb = feature + (size_t)b * 32 * NPTS + (pt & (NPTS - 1));
    float v[8];
    F8 f0, f1;
#pragma unroll
    for (int j = 0; j < 8; j++) v[j] = fb[(size_t)(8 * h + j) * NPTS];
    f0.u = pk8(v);
#pragma unroll
    for (int j = 0; j < 8; j++) v[j] = fb[(size_t)(16 + 8 * h + j) * NPTS];
    f1.u = pk8(v);
    *(uint4*)(t2 + (size_t)pt * 32 + 8 * h) = f0.u;
    *(uint4*)(t2 + (size_t)pt * 32 + 16 + 8 * h) = f1.u;
    float16 acc = z;
    acc = __builtin_amdgcn_mfma_f32_32x32x16_bf16(a0.s, f0.s, acc, 0, 0, 0);
    acc = __builtin_amdgcn_mfma_f32_32x32x16_bf16(a1.s, f1.s, acc, 0, 0, 0);
#pragma unroll
    for (int q = 0; q < 4; q++) {
        int r = 4 * q;
        uint2 uu;
        uu.x = pk2(relu(acc[r] + b2v[r]), relu(acc[r + 1] + b2v[r + 1]));
        uu.y = pk2(relu(acc[r + 2] + b2v[r + 2]), relu(acc[r + 3] + b2v[r + 3]));
        *(uint2*)(t1a + (size_t)pt * 32 + 8 * q + 4 * h) = uu;
    }
}

// ===== K1: tnet head (butterfly matvec, per wave) + f_xyz =====
__global__ __launch_bounds__(256) void kP1(
    const float* __restrict__ xyz,
    const float* __restrict__ tW3, const float* __restrict__ ts3, const float* __restrict__ tb3,
    const float* __restrict__ tW4, const float* __restrict__ tb4,
    const float* __restrict__ W1,  const float* __restrict__ s1, const float* __restrict__ b1,
    char* ws)
{
    const float* stripe = (const float*)(ws + WS_STRIPE);
    unsigned short* t1b = (unsigned short*)(ws + WS_T1B);
    const int lane = threadIdx.x & 63, wv = threadIdx.x >> 6;
    const int col = lane & 31, h = lane >> 5;
    const int u = blockIdx.x;
    const int b = u >> 9;
    float hm = 0.f;                             // stripes >= 0; 0-init safe under max
#pragma unroll
    for (int s = 0; s < 16; s++)
        hm = fmaxf(hm, stripe[s * 128 + b * 64 + lane]);
    float v[16];                                // lane i contributes hm_i * tW3[i][:]
    const float4* trow = (const float4*)(tW3 + lane * 16);
#pragma unroll
    for (int q = 0; q < 4; q++) {
        float4 t4 = trow[q];
        v[4 * q + 0] = hm * t4.x; v[4 * q + 1] = hm * t4.y;
        v[4 * q + 2] = hm * t4.z; v[4 * q + 3] = hm * t4.w;
    }
#pragma unroll
    for (int off = 1; off < 64; off <<= 1) {
#pragma unroll
        for (int c = 0; c < 16; c++) v[c] += __shfl_xor(v[c], off);
    }
    float T[9];
#pragma unroll
    for (int j = 0; j < 9; j++) T[j] = tb4[j];
#pragma unroll
    for (int c = 0; c < 16; c++) {
        float h3 = relu(v[c] * ts3[c] + tb3[c]);
#pragma unroll
        for (int j = 0; j < 9; j++) T[j] += h3 * tW4[c * 9 + j];
    }
    T[0] += 1.f; T[4] += 1.f; T[8] += 1.f;

    int pt = u * 128 + wv * 32 + col;
    const float* xp = xyz + (size_t)pt * 3;
    float x0 = xp[0], x1 = xp[1], x2 = xp[2];
    float q0 = x0 * T[0] + x1 * T[3] + x2 * T[6];
    float q1 = x0 * T[1] + x1 * T[4] + x2 * T[7];
    float q2 = x0 * T[2] + x1 * T[5] + x2 * T[8];
    float r0 = relu((q0 * W1[0] + q1 * W1[3] + q2 * W1[6]) * s1[0] + b1[0]);
    float r1 = relu((q0 * W1[1] + q1 * W1[4] + q2 * W1[7]) * s1[1] + b1[1]);
    float r2 = relu((q0 * W1[2] + q1 * W1[5] + q2 * W1[8]) * s1[2] + b1[2]);
    if (h == 0) {
        uint2 uu; uu.x = pk2(r0, r1); uu.y = pk2(r2, 0.f);
        *(uint2*)(t1b + (size_t)pt * 4) = uu;
    }
}

// ===== K23: gather GEMM + max-over-K (m via LDS, same-wave) + output GEMM =====
__global__ __launch_bounds__(256) void kP23(
    const int* __restrict__ nidx,
    const float* __restrict__ W3, const float* __restrict__ s3, const float* __restrict__ b3,
    const float* __restrict__ W4, const float* __restrict__ s4, const float* __restrict__ b4,
    char* ws, float* __restrict__ out)
{
    __shared__ unsigned short mld[128 * 36];
    const unsigned short* t1a = (const unsigned short*)(ws + WS_T1A);
    const unsigned short* t1b = (const unsigned short*)(ws + WS_T1B);
    const unsigned short* t2  = (const unsigned short*)(ws + WS_T2);
    const int lane = threadIdx.x & 63, wv = threadIdx.x >> 6;
    const int col = lane & 31, h = lane >> 5;
    const float16 z = zero16();
    float e[8];
    // W3^T folded B-frags (k>=35 zero)
    F8 w0, w1, w2, zf;
    zf.u.x = zf.u.y = zf.u.z = zf.u.w = 0u;
    float sc3 = s3[col];
#pragma unroll
    for (int j = 0; j < 8; j++) e[j] = W3[(8 * h + j) * 32 + col] * sc3;
    w0.u = pk8(e);
#pragma unroll
    for (int j = 0; j < 8; j++) e[j] = W3[(16 + 8 * h + j) * 32 + col] * sc3;
    w1.u = pk8(e);
    w2 = zf;
    if (h == 0) {
        float e2[8] = {0.f, 0.f, 0.f, 0.f, 0.f, 0.f, 0.f, 0.f};
#pragma unroll
        for (int j = 0; j < 3; j++) e2[j] = W3[(32 + j) * 32 + col] * sc3;
        w2.u = pk8(e2);
    }
    float b3v = b3[col];
    // W4^T folded A-frags
    F8 aw[4];
    float sc4 = s4[col];
#pragma unroll
    for (int t = 0; t < 4; t++) {
#pragma unroll
        for (int j = 0; j < 8; j++) e[j] = W4[(16 * t + 8 * h + j) * 32 + col] * sc4;
        aw[t].u = pk8(e);
    }
    float b4v[16];
#pragma unroll
    for (int r = 0; r < 16; r++) b4v[r] = b4[(r & 3) + 8 * (r >> 2) + 4 * h];

    // XCD-batch affinity: blk&7 is XCD slot; slot>=4 -> batch 1
    int slot = blockIdx.x & 7, batch = slot >> 2;
    int grp = (blockIdx.x >> 3) * 4 + (slot & 3);   // [0, 512) within batch
    int u = batch * 512 + grp;
    int base = u * 128;

    // preload all 16 neighbor indices (independent loads, issued together)
    int idxs[16];
#pragma unroll
    for (int it = 0; it < 16; it++)
        idxs[it] = nidx[(base + 2 * (wv * 16 + it)) * 16 + col];

    // register double-buffered gather loop: next iteration's loads in flight
    F8 na0, na1, na2;
    {
        size_t row = ((size_t)batch << 16) + (unsigned)idxs[0];
        const unsigned short* ap = t1a + row * 32;
        na0.u = *(const uint4*)(ap + 8 * h);
        na1.u = *(const uint4*)(ap + 16 + 8 * h);
        na2 = zf;
        if (h == 0) { uint2 q = *(const uint2*)(t1b + row * 4); na2.u.x = q.x; na2.u.y = q.y; }
    }
    for (int it = 0; it < 16; it++) {
        F8 ca0 = na0, ca1 = na1, ca2 = na2;
        if (it < 15) {
            size_t row = ((size_t)batch << 16) + (unsigned)idxs[it + 1];
            const unsigned short* ap = t1a + row * 32;
            na0.u = *(const uint4*)(ap + 8 * h);
            na1.u = *(const uint4*)(ap + 16 + 8 * h);
            na2 = zf;
            if (h == 0) { uint2 q = *(const uint2*)(t1b + row * 4); na2.u.x = q.x; na2.u.y = q.y; }
        }
        float16 acc = z;
        acc = __builtin_amdgcn_mfma_f32_32x32x16_bf16(ca0.s, w0.s, acc, 0, 0, 0);
        acc = __builtin_amdgcn_mfma_f32_32x32x16_bf16(ca1.s, w1.s, acc, 0, 0, 0);
        acc = __builtin_amdgcn_mfma_f32_32x32x16_bf16(ca2.s, w2.s, acc, 0, 0, 0);
        float vA = acc[0], vB = acc[8];
#pragma unroll
        for (int r = 1; r < 8; r++) { vA = fmaxf(vA, acc[r]); vB = fmaxf(vB, acc[8 + r]); }
        vA = fmaxf(vA, __shfl_xor(vA, 32));
        vB = fmaxf(vB, __shfl_xor(vB, 32));
        vA = relu(vA + b3v);
        vB = relu(vB + b3v);
        float val = h ? vB : vA;
        int pi = wv * 16 + it;
        mld[(2 * pi + h) * 36 + col] = f2bf(val);    // same-wave produce/consume
    }

    // output GEMM: 32 pts per wave; m read from LDS (same wave -> no barrier)
    int p_loc = wv * 32 + col;
    int p = base + p_loc;
    const unsigned short* bp = t2 + (size_t)p * 32 + 8 * h;
    F8 x0, x1, x2, x3;
    x0.u = *(const uint4*)(bp);
    x1.u = *(const uint4*)(bp + 16);
    const unsigned short* mp = mld + p_loc * 36;
    uint2 q0 = *(const uint2*)(mp + 8 * h);
    uint2 q1 = *(const uint2*)(mp + 8 * h + 4);
    uint2 q2 = *(const uint2*)(mp + 16 + 8 * h);
    uint2 q3 = *(const uint2*)(mp + 16 + 8 * h + 4);
    x2.u.x = q0.x; x2.u.y = q0.y; x2.u.z = q1.x; x2.u.w = q1.y;
    x3.u.x = q2.x; x3.u.y = q2.y; x3.u.z = q3.x; x3.u.w = q3.y;
    float16 acc = z;
    acc = __builtin_amdgcn_mfma_f32_32x32x16_bf16(aw[0].s, x0.s, acc, 0, 0, 0);
    acc = __builtin_amdgcn_mfma_f32_32x32x16_bf16(aw[1].s, x1.s, acc, 0, 0, 0);
    acc = __builtin_amdgcn_mfma_f32_32x32x16_bf16(aw[2].s, x2.s, acc, 0, 0, 0);
    acc = __builtin_amdgcn_mfma_f32_32x32x16_bf16(aw[3].s, x3.s, acc, 0, 0, 0);
    float* ob = out + (size_t)(batch * 32) * NPTS + (p & (NPTS - 1));
#pragma unroll
    for (int r = 0; r < 16; r++) {
        int o = (r & 3) + 8 * (r >> 2) + 4 * h;
        ob[(size_t)o * NPTS] = relu(acc[r] + b4v[r]);
    }
}

extern "C" void kernel_launch(void* const* d_in, const int* in_sizes, int n_in,
                              void* d_out, int out_size, void* d_ws, size_t ws_size,
                              hipStream_t stream)
{
    const float* feature = (const float*)d_in[0];
    const float* xyz     = (const float*)d_in[1];
    const int*   nidx    = (const int*)d_in[2];
    const float* tW1 = (const float*)d_in[3];
    const float* ts1 = (const float*)d_in[4];
    const float* tb1 = (const float*)d_in[5];
    const float* tW2 = (const float*)d_in[6];
    const float* ts2 = (const float*)d_in[7];
    const float* tb2 = (const float*)d_in[8];
    const float* tW3 = (const float*)d_in[9];
    const float* ts3 = (const float*)d_in[10];
    const float* tb3 = (const float*)d_in[11];
    const float* tW4 = (const float*)d_in[12];
    const float* tb4 = (const float*)d_in[13];
    const float* W1  = (const float*)d_in[14];
    const float* s1  = (const float*)d_in[15];
    const float* b1  = (const float*)d_in[16];
    const float* W2  = (const float*)d_in[17];
    const float* s2  = (const float*)d_in[18];
    const float* b2  = (const float*)d_in[19];
    const float* W3  = (const float*)d_in[20];
    const float* s3  = (const float*)d_in[21];
    const float* b3  = (const float*)d_in[22];
    const float* W4  = (const float*)d_in[23];
    const float* s4  = (const float*)d_in[24];
    const float* b4  = (const float*)d_in[25];
    (void)in_sizes; (void)n_in; (void)out_size; (void)ws_size;

    char* wsp = (char*)d_ws;
    float* outp = (float*)d_out;

    hipMemsetAsync(wsp + WS_STRIPE, 0, 16 * 128 * sizeof(float), stream);
    kP0<<<NUNITS, 256, 0, stream>>>(feature, xyz, tW1, ts1, tb1, tW2, ts2, tb2,
                                    W2, s2, b2, wsp);
    kP1<<<NUNITS, 256, 0, stream>>>(xyz, tW3, ts3, tb3, tW4, tb4, W1, s1, b1, wsp);
    kP23<<<NUNITS, 256, 0, stream>>>(nidx, W3, s3, b3, W4, s4, b4, wsp, outp);
}